// Round 12
// baseline (174.987 us; speedup 1.0000x reference)
//
#include <hip/hip_runtime.h>
#include <hip/hip_bf16.h>

#define B_SIZE 4096
#define D_SIZE 256
#define N_SIZE 8192
#define LOG2E10 14.4269504089f     // 10 * log2(e):  exp(10x) = exp2(x * LOG2E10)

#if __has_builtin(__builtin_amdgcn_exp2f)
#define FAST_EXP2(x) __builtin_amdgcn_exp2f(x)
#else
#define FAST_EXP2(x) exp2f(x)
#endif

typedef __attribute__((ext_vector_type(8))) short short8;
typedef __attribute__((ext_vector_type(4))) short short4v;
typedef __attribute__((ext_vector_type(4))) float floatx4;

// ws layout (bytes):
//       0 : float Sarr[2*8192]        (65536)  per-row full exp-sum (incl diag)
//   65536 : float lossAcc; int ticket (8)
//  524288 : bf16 featS|featT0|featT1  (3 x 2MB contiguous)

__device__ __forceinline__ void async16(void* lds, const void* g) {
    __builtin_amdgcn_global_load_lds(
        (const __attribute__((address_space(1))) unsigned int*)g,
        (__attribute__((address_space(3))) unsigned int*)lds, 16, 0, 0);
}

// q in [0,496) -> (R,C) with 0 <= C < R <= 31 (strictly lower triangle)
__device__ __forceinline__ void pair_from_q(int q, int& R, int& C) {
    int r = (int)((1.0f + sqrtf(1.0f + 8.0f * (float)q)) * 0.5f);
    while (r * (r - 1) / 2 > q) --r;
    while ((r + 1) * r / 2 <= q) ++r;
    R = r; C = q - r * (r - 1) / 2;
}

// Wave-per-row normalize (float4). 3072 blocks x 256.
__global__ void norm_kernel(const float* __restrict__ hs,
                            const float* __restrict__ ht0,
                            const float* __restrict__ ht1,
                            __hip_bfloat16* __restrict__ dst,
                            float* __restrict__ zero_region) {
    const int tid = threadIdx.x;
    const int wv  = tid >> 6;
    const int l   = tid & 63;
    const int gid = blockIdx.x * 256 + tid;
    if (gid < 16386) zero_region[gid] = 0.0f;   // Sarr + lossAcc + ticket

    const int row = blockIdx.x * 4 + wv;        // 0..12287
    const float* src = (row < 4096) ? (hs + row * D_SIZE)
                     : (row < 8192) ? (ht0 + (row - 4096) * D_SIZE)
                                    : (ht1 + (row - 8192) * D_SIZE);
    floatx4 x = *reinterpret_cast<const floatx4*>(src + l * 4);
    float ss = x[0] * x[0] + x[1] * x[1] + x[2] * x[2] + x[3] * x[3];
#pragma unroll
    for (int off = 32; off > 0; off >>= 1) ss += __shfl_xor(ss, off);
    float inv = 1.0f / fmaxf(sqrtf(ss), 1e-12f);
    short4v o;
#pragma unroll
    for (int k = 0; k < 4; ++k) {
        __hip_bfloat16 h = __float2bfloat16(x[k] * inv);
        o[k] = *reinterpret_cast<short*>(&h);
    }
    *reinterpret_cast<short4v*>(dst + row * D_SIZE + l * 4) = o;
}

// Symmetric S-only sim kernel, 512-thread blocks for 16 waves/CU.
// Block: 8 waves x 32 rows = 256 rows; cols in 8 LDS-staged 32-col groups
// (dbuf 2x16KB, MFMA-fragment order, conflict-free). Wave owns rt=2 row-tiles
// (af[2][8] = 64 VGPR -> no spill at launch_bounds(512,2) = 16 waves/CU).
// Grid 1056: blocks 0..991 below-diag (R,C,t) pairs (heavy, first);
// 992..1055 diagonal blocks (light, last -> tail back-fill).
// Diagonal-crossing tiles are exact 32x32 symmetric squares: row-sums only.
__global__ __launch_bounds__(512, 2)
void sim_kernel(const __hip_bfloat16* __restrict__ featS,
                const __hip_bfloat16* __restrict__ featT0,
                const __hip_bfloat16* __restrict__ featT1,
                float* __restrict__ Sarr) {
    __shared__ __align__(16) unsigned char sB[2][16384];

    int R, C, t;
    if (blockIdx.x < 992) {
        t = blockIdx.x & 1;
        pair_from_q(blockIdx.x >> 1, R, C);
    } else {
        int i = blockIdx.x - 992;   // 0..63
        t = i & 1;
        R = C = i >> 1;             // 0..31
    }
    const __hip_bfloat16* featT = t ? featT1 : featT0;

    const int tid  = threadIdx.x;
    const int w    = tid >> 6;      // 0..7
    const int l    = tid & 63;
    const int quad = l >> 4;
    const int lcol = l & 15;
    const int row_base = R * 256 + w * 32;
    const int col0 = C * 256;

    // A fragments: 2 row-tiles x 8 k-steps (64 VGPR), register resident
    short8 af[2][8];
#pragma unroll
    for (int rt = 0; rt < 2; ++rt) {
        int arow = row_base + rt * 16 + lcol;
        const __hip_bfloat16* ap = (arow < B_SIZE) ? featS + arow * D_SIZE
                                                   : featT + (arow - B_SIZE) * D_SIZE;
#pragma unroll
        for (int ks = 0; ks < 8; ++ks)
            af[rt][ks] = *reinterpret_cast<const short8*>(ap + ks * 32 + quad * 8);
    }

    float Sp[2][4];
#pragma unroll
    for (int rt = 0; rt < 2; ++rt)
#pragma unroll
        for (int r = 0; r < 4; ++r) Sp[rt][r] = 0.0f;

    // stage one 32-col group (16 KB): wave w covers u-tile (w&1), ks pair (w>>1)*2.
    // lane l fetches col tb+(l&15), k-bytes (l>>4)*16+ks*64 -> LDS base + l*16.
    auto stage = [&](int b, int cb) {
        const int u   = w & 1;
        const int ks0 = (w >> 1) * 2;
        const int tb  = cb + u * 16;
        const __hip_bfloat16* cp = (tb < B_SIZE) ? featS + tb * D_SIZE
                                                 : featT + (tb - B_SIZE) * D_SIZE;
        const char* gp = (const char*)cp + (l & 15) * 512 + (l >> 4) * 16;
        unsigned char* lp = &sB[b][u * 8192];
#pragma unroll
        for (int kk = 0; kk < 2; ++kk) {
            int ks = ks0 + kk;
            async16(lp + ks * 1024, gp + ks * 64);
        }
    };

    stage(0, col0);

    for (int g = 0; g < 8; ++g) {
        const int buf = g & 1;
        __syncthreads();                               // drains DMA for buf
        if (g + 1 < 8) stage(buf ^ 1, col0 + (g + 1) * 32);

        const int gcol = col0 + g * 32;
        if (gcol > row_base) continue;                 // above diagonal: skip
        const bool dg = (gcol == row_base);            // exact symmetric square

        floatx4 acc[2][2];                             // [j][rt]
#pragma unroll
        for (int j = 0; j < 2; ++j)
#pragma unroll
            for (int rt = 0; rt < 2; ++rt) acc[j][rt] = floatx4{0.f, 0.f, 0.f, 0.f};

#pragma unroll
        for (int ks = 0; ks < 8; ++ks) {
            short8 bf[2];
#pragma unroll
            for (int j = 0; j < 2; ++j)
                bf[j] = *reinterpret_cast<const short8*>(
                    &sB[buf][j * 8192 + ks * 1024 + l * 16]);
#pragma unroll
            for (int j = 0; j < 2; ++j)
#pragma unroll
                for (int rt = 0; rt < 2; ++rt)
                    acc[j][rt] = __builtin_amdgcn_mfma_f32_16x16x32_bf16(
                        af[rt][ks], bf[j], acc[j][rt], 0, 0, 0);
        }

        float Cp[2] = {0.f, 0.f};
#pragma unroll
        for (int j = 0; j < 2; ++j)
#pragma unroll
            for (int rt = 0; rt < 2; ++rt)
#pragma unroll
                for (int r = 0; r < 4; ++r) {
                    float e = FAST_EXP2(acc[j][rt][r] * LOG2E10);
                    Sp[rt][r] += e;
                    Cp[j] += e;
                }

        if (!dg) {   // strictly below diagonal: mirror to column row-sums
#pragma unroll
            for (int j = 0; j < 2; ++j) {
                Cp[j] += __shfl_xor(Cp[j], 16);
                Cp[j] += __shfl_xor(Cp[j], 32);
            }
            if (quad == 0) {
#pragma unroll
                for (int j = 0; j < 2; ++j)
                    atomicAdd(&Sarr[t * N_SIZE + gcol + j * 16 + lcol], Cp[j]);
            }
        }
    }

    // row-sum flush: reduce over the 16 col-lanes of each quad
#pragma unroll
    for (int rt = 0; rt < 2; ++rt)
#pragma unroll
        for (int r = 0; r < 4; ++r) {
#pragma unroll
            for (int m = 1; m < 16; m <<= 1) Sp[rt][r] += __shfl_xor(Sp[rt][r], m);
        }
    if (lcol == 0) {
#pragma unroll
        for (int rt = 0; rt < 2; ++rt)
#pragma unroll
            for (int r = 0; r < 4; ++r) {
                int row = row_base + rt * 16 + quad * 4 + r;
                atomicAdd(&Sarr[t * N_SIZE + row], Sp[rt][r]);
            }
    }
}

// Per-class stats + final loss (fused gvec + rowstat). 128 blocks x 256.
// g-accumulation wave-parallel: wave wv takes members wv, wv+4, ...; lane l
// owns dims 4l..4l+3; partials combined via LDS atomics.
__global__ void classstat_kernel(const __hip_bfloat16* __restrict__ featS,
                                 const __hip_bfloat16* __restrict__ featT0,
                                 const __hip_bfloat16* __restrict__ featT1,
                                 const int* __restrict__ labels,
                                 const float* __restrict__ Sarr,
                                 float* __restrict__ lossAcc,
                                 int* __restrict__ ticket,
                                 float* __restrict__ out) {
    __shared__ int idx[256];
    __shared__ int nsh;
    __shared__ float gS[256], gT0[256], gT1[256];
    __shared__ float wpart[4];

    const int c   = blockIdx.x;
    const int tid = threadIdx.x;
    const int wv  = tid >> 6;
    const int l   = tid & 63;

    if (tid == 0) nsh = 0;
    gS[tid] = 0.f; gT0[tid] = 0.f; gT1[tid] = 0.f;
    __syncthreads();
    for (int i = tid; i < B_SIZE; i += 256)
        if ((labels[i] & 127) == c) { int p = atomicAdd(&nsh, 1); idx[p] = i; }
    __syncthreads();
    const int n = nsh;

    {   // wave-parallel g accumulation
        float aS[4] = {0,0,0,0}, a0[4] = {0,0,0,0}, a1[4] = {0,0,0,0};
        for (int m = wv; m < n; m += 4) {
            int base = idx[m] * D_SIZE + l * 4;
            short4v bS = *reinterpret_cast<const short4v*>(featS + base);
            short4v b0 = *reinterpret_cast<const short4v*>(featT0 + base);
            short4v b1 = *reinterpret_cast<const short4v*>(featT1 + base);
#pragma unroll
            for (int k = 0; k < 4; ++k) {
                aS[k] += __uint_as_float(((unsigned int)(unsigned short)bS[k]) << 16);
                a0[k] += __uint_as_float(((unsigned int)(unsigned short)b0[k]) << 16);
                a1[k] += __uint_as_float(((unsigned int)(unsigned short)b1[k]) << 16);
            }
        }
#pragma unroll
        for (int k = 0; k < 4; ++k) {
            atomicAdd(&gS[l * 4 + k],  aS[k]);
            atomicAdd(&gT0[l * 4 + k], a0[k]);
            atomicAdd(&gT1[l * 4 + k], a1[k]);
        }
    }
    __syncthreads();

    float psum = 0.0f;
    const float M = 2.0f * (float)n - 1.0f;
    // instance = m*4 + half*2 + t : row (half? 4096+i : i) of teacher-t problem
    for (int inst = wv; inst < 4 * n; inst += 4) {
        const int t    = inst & 1;
        const int half = (inst >> 1) & 1;
        const int i    = idx[inst >> 2];
        const __hip_bfloat16* f = half ? ((t ? featT1 : featT0) + i * D_SIZE)
                                       : (featS + i * D_SIZE);
        short4v fb = *reinterpret_cast<const short4v*>(f + l * 4);
        const float* gT = t ? gT1 : gT0;
        float dot = 0.f, aii = 0.f;
#pragma unroll
        for (int k = 0; k < 4; ++k) {
            float fx = __uint_as_float(((unsigned int)(unsigned short)fb[k]) << 16);
            dot += fx * (gS[l * 4 + k] + gT[l * 4 + k]);
            aii += fx * fx;
        }
#pragma unroll
        for (int m = 1; m < 64; m <<= 1) {
            dot += __shfl_xor(dot, m);
            aii += __shfl_xor(aii, m);
        }
        if (l == 0) {
            int row = half ? (B_SIZE + i) : i;
            float S = Sarr[t * N_SIZE + row];
            float E = FAST_EXP2(LOG2E10 * aii);
            psum += logf(S - E) - 10.0f * (dot - aii) / M;
        }
    }
    if (l == 0) wpart[wv] = psum;
    __syncthreads();
    if (tid == 0) {
        atomicAdd(lossAcc, wpart[0] + wpart[1] + wpart[2] + wpart[3]);
        __threadfence();
        if (atomicAdd(ticket, 1) == 127) {
            float tot = atomicAdd(lossAcc, 0.0f);   // read-after-all-adds
            out[0] = tot / 16384.0f;
        }
    }
}

extern "C" void kernel_launch(void* const* d_in, const int* in_sizes, int n_in,
                              void* d_out, int out_size, void* d_ws, size_t ws_size,
                              hipStream_t stream) {
    const float* hs     = (const float*)d_in[0];
    const float* ht0    = (const float*)d_in[1];
    const float* ht1    = (const float*)d_in[2];
    const int*   labels = (const int*)d_in[3];

    char* ws = (char*)d_ws;
    float* Sarr    = (float*)(ws);
    float* lossAcc = (float*)(ws + 65536);
    int*   ticket  = (int*)(ws + 65540);
    __hip_bfloat16* featS  = (__hip_bfloat16*)(ws + 524288);
    __hip_bfloat16* featT0 = (__hip_bfloat16*)(ws + 524288 + 2097152);
    __hip_bfloat16* featT1 = (__hip_bfloat16*)(ws + 524288 + 2 * 2097152);

    norm_kernel<<<3072, 256, 0, stream>>>(hs, ht0, ht1, featS, (float*)ws);
    sim_kernel<<<1056, 512, 0, stream>>>(featS, featT0, featT1, Sarr);
    classstat_kernel<<<128, 256, 0, stream>>>(featS, featT0, featT1, labels,
                                              Sarr, lossAcc, ticket, (float*)d_out);
}